// Round 16
// baseline (162.990 us; speedup 1.0000x reference)
//
#include <hip/hip_runtime.h>
#include <hip/hip_bf16.h>
#include <math.h>

// Problem constants
#define BATCH 2
#define SEQ   2048
#define DIM   1024
#define HEADS 16
#define DH    64
#define MROWS (BATCH*SEQ)      // 4096
#define NTOT  3072             // gemm output cols: q(1024) | k(1024) | v(1024)
#define KDIM  1024

typedef float f32x4 __attribute__((ext_vector_type(4)));
typedef __bf16 bf16x8 __attribute__((ext_vector_type(8)));
typedef __bf16 bf16x4 __attribute__((ext_vector_type(4)));

// ALL tensor buffers are MFMA-fragment-order: 1KB block = 64 lanes x 16B; lane ln=quad*16+r
// holds (r = row&15, k = quad*8 + j) of a 16row x 32K operand tile.
//  xbF: block g*32 + c        g = token-group (16 rows), c = K-chunk (32)
//  WtF: block gn*32 + c       gn = output-col-group
//  qF/kF: block ((b*128+g)*16 + h)*2 + kf
//  vF   : block ((bh*32+kvt)*4 + nb)*2 + kf
// One block == one global_load_lds (wave-uniform dest, lane*16B) == one natural b128 read.

__device__ __forceinline__ void gload_lds16(const void* g, void* l) {
    __builtin_amdgcn_global_load_lds((__attribute__((address_space(1))) void*)g,
                                     (__attribute__((address_space(3))) void*)l,
                                     16, 0, 0);
}

// ---------------------------------------------- prep: cast x -> xbF  +  transpose W -> WtF
__global__ void prep_kernel(const float* __restrict__ x,
                            const float* __restrict__ Wqk, const float* __restrict__ Wv,
                            __bf16* __restrict__ xbF, __bf16* __restrict__ WtF) {
    __shared__ float T[64*65];
    const int bx = blockIdx.x;
    const int tid = threadIdx.x;
    if (bx < 4096) {
        int i = bx * 256 + tid;                   // 1M float4 = 4M floats exactly
        float4 f = ((const float4*)x)[i];
        bf16x4 o;
        o.x = (__bf16)f.x; o.y = (__bf16)f.y; o.z = (__bf16)f.z; o.w = (__bf16)f.w;
        int row = i >> 8, k4 = (i & 255) << 2;    // x is (4096,1024)
        int g = row >> 4, r = row & 15;
        int c = k4 >> 5, quad = (k4 >> 3) & 3, j0 = k4 & 7;
        *(bf16x4*)&xbF[((size_t)(g*32 + c))*512 + (quad*16 + r)*8 + j0] = o;
    } else {
        const int t = bx - 4096;                  // 0..767
        const int n0 = (t % 48) * 64;
        const int k0 = (t / 48) * 64;
#pragma unroll
        for (int i = 0; i < 16; ++i) {
            int idx = i*256 + tid;
            int kk = idx >> 6, nn = idx & 63;
            int n = n0 + nn;
            float v = (n < 2048) ? Wqk[(size_t)(k0+kk)*2048 + n]
                                 : Wv [(size_t)(k0+kk)*1024 + (n - 2048)];
            T[kk*65 + nn] = v;
        }
        __syncthreads();
#pragma unroll
        for (int i = 0; i < 16; ++i) {
            int idx = i*256 + tid;
            int nn = idx >> 6, kk = idx & 63;     // 64 lanes share one n, k consecutive
            int n = n0 + nn, k = k0 + kk;
            int gn = n >> 4, rn = n & 15;
            int c = k >> 5, quad = (k >> 3) & 3, j = k & 7;
            WtF[((size_t)(gn*32 + c))*512 + (quad*16 + rn)*8 + j] = (__bf16)T[kk*65 + nn];
        }
    }
}

// ---------------------------------------------------------------- GEMM v8: producer/consumer waves
// 320 thr = 4 compute waves + 1 PRODUCER wave. Producer issues all global_load_lds into the
// double-buffered LDS; its per-wave vmcnt(0) drain at each __syncthreads overlaps the
// consumers' compute (consumers have ZERO outstanding VMEM -> their barrier drain is free).
// One barrier per K-iter. K order identical to r15 -> bit-identical accumulation.
#define BM 128
#define BN 128

__global__ __launch_bounds__(320) void gemm_qkv_kernel(const __bf16* __restrict__ xbF,
                                                       const __bf16* __restrict__ WtF,
                                                       const float* __restrict__ bqk,
                                                       const float* __restrict__ bv,
                                                       __bf16* __restrict__ qF,
                                                       __bf16* __restrict__ kF,
                                                       __bf16* __restrict__ vF) {
    __shared__ alignas(16) __bf16 As[2][16*512];  // dbuf, 2 x 16 KB
    __shared__ alignas(16) __bf16 Bs[2][16*512];  // 64 KB total -> 2 blocks/CU
    const int tid = threadIdx.x;
    const int wv = tid >> 6, ln = tid & 63;
    const int quad = ln >> 4, lm = ln & 15;
    const int m0 = blockIdx.y * BM, n0 = blockIdx.x * BN;
    const int mg0 = m0 >> 4, ng0 = n0 >> 4;

    if (wv == 4) {
        // ---------------- producer wave ----------------
        auto stage = [&](int kt, int buf) {
#pragma unroll
            for (int s = 0; s < 16; ++s)
                gload_lds16(xbF + ((size_t)((mg0 + (s >> 1))*32 + kt*2 + (s & 1)))*512 + (size_t)ln*8,
                            &As[buf][s*512]);
#pragma unroll
            for (int u = 0; u < 16; ++u)
                gload_lds16(WtF + ((size_t)((ng0 + (u >> 1))*32 + kt*2 + (u & 1)))*512 + (size_t)ln*8,
                            &Bs[buf][u*512]);
        };
        stage(0, 0);
        for (int kt = 0; kt < KDIM/64; ++kt) {
            __syncthreads();                      // own vmcnt(0): stage(kt) ready; rendezvous
            if (kt + 1 < KDIM/64) stage(kt + 1, (kt + 1) & 1);
        }
        return;                                   // barrier counts matched (16 each side)
    }

    // ---------------- consumer waves 0..3 ----------------
    const int wm = (wv >> 1) * 64, wn = (wv & 1) * 64;
    f32x4 acc[4][4] = {};

    if (n0 < 2048) {
        // q/k path: acc[nt][mt] = C^T tiles
        for (int kt = 0; kt < KDIM/64; ++kt) {
            __syncthreads();                      // no own VMEM -> free drain
            const int cur = kt & 1;
#pragma unroll
            for (int kf = 0; kf < 2; ++kf) {
                bf16x8 af[4], bfr[4];
#pragma unroll
                for (int mt = 0; mt < 4; ++mt)
                    af[mt] = *(const bf16x8*)&As[cur][(((wm >> 4) + mt)*2 + kf)*512 + ln*8];
#pragma unroll
                for (int nt = 0; nt < 4; ++nt)
                    bfr[nt] = *(const bf16x8*)&Bs[cur][(((wn >> 4) + nt)*2 + kf)*512 + ln*8];
#pragma unroll
                for (int nt = 0; nt < 4; ++nt)
#pragma unroll
                    for (int mt = 0; mt < 4; ++mt)
                        acc[nt][mt] = __builtin_amdgcn_mfma_f32_16x16x32_bf16(bfr[nt], af[mt], acc[nt][mt], 0, 0, 0);
            }
        }
        __bf16* dst = (n0 < 1024) ? qF : kF;      // block-uniform
#pragma unroll
        for (int nt = 0; nt < 4; ++nt) {
            int f = n0 + wn + nt*16 + quad*4;
            float4 bs4 = *(const float4*)&bqk[f];
            int fl = f & 1023;
            int h  = fl >> 6;
            int ff = fl & 63;
            int fquad = (ff >> 3) & 3;
            int j0 = ff & 7;
            int kf = ff >> 5;
#pragma unroll
            for (int mt = 0; mt < 4; ++mt) {
                int m = m0 + wm + mt*16 + lm;
                int b = m >> 11, g = (m & 2047) >> 4;
                bf16x4 pk;
                pk[0] = (__bf16)(acc[nt][mt][0] + bs4.x);
                pk[1] = (__bf16)(acc[nt][mt][1] + bs4.y);
                pk[2] = (__bf16)(acc[nt][mt][2] + bs4.z);
                pk[3] = (__bf16)(acc[nt][mt][3] + bs4.w);
                size_t blk = (((size_t)(b*128 + g)*16 + h)*2 + kf);
                *(bf16x4*)&dst[blk*512 + (fquad*16 + lm)*8 + j0] = pk;
            }
        }
    } else {
        // v path: acc[mt][nt] = C tiles -> vF frag-order
        for (int kt = 0; kt < KDIM/64; ++kt) {
            __syncthreads();
            const int cur = kt & 1;
#pragma unroll
            for (int kf = 0; kf < 2; ++kf) {
                bf16x8 af[4], bfr[4];
#pragma unroll
                for (int mt = 0; mt < 4; ++mt)
                    af[mt] = *(const bf16x8*)&As[cur][(((wm >> 4) + mt)*2 + kf)*512 + ln*8];
#pragma unroll
                for (int nt = 0; nt < 4; ++nt)
                    bfr[nt] = *(const bf16x8*)&Bs[cur][(((wn >> 4) + nt)*2 + kf)*512 + ln*8];
#pragma unroll
                for (int mt = 0; mt < 4; ++mt)
#pragma unroll
                    for (int nt = 0; nt < 4; ++nt)
                        acc[mt][nt] = __builtin_amdgcn_mfma_f32_16x16x32_bf16(af[mt], bfr[nt], acc[mt][nt], 0, 0, 0);
            }
        }
#pragma unroll
        for (int mt = 0; mt < 4; ++mt) {
            int s4 = m0 + wm + mt*16 + quad*4;
            int b   = s4 >> 11;
            int kvt = (s4 & 2047) >> 6;
            int kv  = s4 & 63;
            int kf  = kv >> 5;
            int qv  = (kv >> 3) & 3;
            int j0  = kv & 7;
#pragma unroll
            for (int nt = 0; nt < 4; ++nt) {
                int cv = n0 + wn + nt*16 + lm - 2048;
                int h = cv >> 6, dv = cv & 63, nb = dv >> 4;
                float bs = bv[cv];
                bf16x4 pk;
#pragma unroll
                for (int r = 0; r < 4; ++r) pk[r] = (__bf16)(acc[mt][nt][r] + bs);
                size_t blk = (((size_t)((b*16 + h)*32 + kvt)*4 + nb)*2 + kf);
                *(bf16x4*)&vF[blk*512 + (qv*16 + lm)*8 + j0] = pk;
            }
        }
    }
}

// ---------------------------------------------------------------- flash attention v14
// Producer/consumer wave specialization on the r14 structure: 320 thr = 4 compute waves +
// 1 producer staging frag-order K/V blocks into dbuf LDS. Consumers have zero outstanding
// VMEM at barriers; producer's vmcnt drain overlaps consumer compute. One barrier/step.
// exp2 no-max softmax + ones-MFMA l; balanced qt map. Bit-identical math.
// LDS 40KB -> 4 blocks/CU, 20 waves/CU.

__global__ __launch_bounds__(320) void attn_kernel(const __bf16* __restrict__ qF,
                                                   const __bf16* __restrict__ kF,
                                                   const __bf16* __restrict__ vF,
                                                   float* __restrict__ out) {
    const int bh = blockIdx.x;
    const int b = bh >> 4, h = bh & 15;
    const int y = (int)blockIdx.y;
    const int qt = (y < 8) ? (31 - y) : (y < 16) ? (y - 8) : (y < 24) ? (39 - y) : (y - 16);
    const int qb = qt * 64;
    const int tid = threadIdx.x, wv = tid >> 6, ln = tid & 63;
    const int quad = ln >> 4, lm = ln & 15;
    const int nsteps = qt + 1;

    __shared__ alignas(16) __bf16 Ks[2][8*512];     // [buf][slot nt*2+kf][frag]
    __shared__ alignas(16) __bf16 Vs[2][8*512];     // [buf][slot nb*2+kf][frag]
    __shared__ alignas(16) __bf16 Ps[4][16*64];     // per-consumer-wave P^T, chunk-swizzled

    if (wv == 4) {
        // ---------------- producer wave ----------------
        auto stage = [&](int st, int buf) {
#pragma unroll
            for (int idx = 0; idx < 8; ++idx) {
                int nt = idx >> 1, kf = idx & 1;
                gload_lds16(kF + ((((size_t)b*128 + st*4 + nt)*16 + h)*2 + kf)*512 + (size_t)ln*8,
                            &Ks[buf][idx*512]);
            }
#pragma unroll
            for (int j = 0; j < 8; ++j) {
                int nb = j >> 1, kf = j & 1;
                gload_lds16(vF + ((((size_t)bh*32 + st)*4 + nb)*2 + kf)*512 + (size_t)ln*8,
                            &Vs[buf][j*512]);
            }
        };
        stage(0, 0);
        for (int st = 0; st < nsteps; ++st) {
            __syncthreads();                      // own vmcnt(0): stage(st) ready
            if (st + 1 < nsteps) stage(st + 1, (st + 1) & 1);
        }
        return;                                   // barrier counts matched (nsteps each side)
    }

    // ---------------- consumer waves 0..3 ----------------
    const int q0w = qb + wv*16;                     // this wave's 16 q-rows
    const int qg = q0w + lm;                        // this lane's q row
    const int sw = lm & 7;                          // P swizzle key

    // Q fragments, pre-scaled by 0.125*log2(e) so P = exp2(S); vmcnt drains at barrier 0
    const float qscale = 0.125f * 1.44269504088896f;
    bf16x8 qf[2];
#pragma unroll
    for (int kf = 0; kf < 2; ++kf) {
        bf16x8 t = *(const bf16x8*)&qF[((((size_t)b*128 + (q0w >> 4))*16 + h)*2 + kf)*512 + ln*8];
#pragma unroll
        for (int j = 0; j < 8; ++j) t[j] = (__bf16)((float)t[j] * qscale);
        qf[kf] = t;
    }
    bf16x8 ones;
#pragma unroll
    for (int j = 0; j < 8; ++j) ones[j] = (__bf16)1.0f;

    f32x4 o[4] = {};                                // O^T: (dv = nb*16+quad*4+r, q = lm)
    f32x4 o5 = {};                                  // l accumulator: every reg = l(q=lm)

    for (int st = 0; st < nsteps; ++st) {
        const int cur = st & 1;
        const int kv0 = st * 64;
        __syncthreads();                            // no own VMEM -> free drain

        // ---- S^T = K Q^T : frag reads are natural b128, conflict-free
        f32x4 s[4] = {};
        bf16x8 kfrag[4][2];
#pragma unroll
        for (int nt = 0; nt < 4; ++nt)
#pragma unroll
            for (int kf = 0; kf < 2; ++kf)
                kfrag[nt][kf] = *(const bf16x8*)&Ks[cur][(nt*2 + kf)*512 + ln*8];
#pragma unroll
        for (int nt = 0; nt < 4; ++nt)
#pragma unroll
            for (int kf = 0; kf < 2; ++kf)
                s[nt] = __builtin_amdgcn_mfma_f32_16x16x32_bf16(kfrag[nt][kf], qf[kf], s[nt], 0, 0, 0);

        // ---- causal mask (diagonal step only; exp2(-1e9)=0)
        if (kv0 + 63 > q0w) {
#pragma unroll
            for (int nt = 0; nt < 4; ++nt)
#pragma unroll
                for (int r = 0; r < 4; ++r) {
                    int kvg = kv0 + nt*16 + quad*4 + r;
                    if (kvg > qg) s[nt][r] = -1e9f;
                }
        }

        // ---- P = exp2(s) -> per-wave LDS (swizzled 8B stores)
#pragma unroll
        for (int nt = 0; nt < 4; ++nt) {
            bf16x4 pb;
#pragma unroll
            for (int r = 0; r < 4; ++r)
                pb[r] = (__bf16)exp2f(s[nt][r]);
            int pos = ((nt*2 + (quad >> 1)) ^ sw);
            *(bf16x4*)&Ps[wv][lm*64 + pos*8 + (quad & 1)*4] = pb;
        }

        // ---- O^T += V^T P^T ; l += 1^T P^T  (wave-local LDS RAW)
        bf16x8 vfrag[4][2];
#pragma unroll
        for (int nb = 0; nb < 4; ++nb)
#pragma unroll
            for (int kf = 0; kf < 2; ++kf)
                vfrag[nb][kf] = *(const bf16x8*)&Vs[cur][(nb*2 + kf)*512 + ln*8];
        bf16x8 pf0 = *(const bf16x8*)&Ps[wv][lm*64 + ((0*4 + quad) ^ sw)*8];
        bf16x8 pf1 = *(const bf16x8*)&Ps[wv][lm*64 + ((1*4 + quad) ^ sw)*8];
#pragma unroll
        for (int nb = 0; nb < 4; ++nb) {
            o[nb] = __builtin_amdgcn_mfma_f32_16x16x32_bf16(vfrag[nb][0], pf0, o[nb], 0, 0, 0);
            o[nb] = __builtin_amdgcn_mfma_f32_16x16x32_bf16(vfrag[nb][1], pf1, o[nb], 0, 0, 0);
        }
        o5 = __builtin_amdgcn_mfma_f32_16x16x32_bf16(ones, pf0, o5, 0, 0, 0);
        o5 = __builtin_amdgcn_mfma_f32_16x16x32_bf16(ones, pf1, o5, 0, 0, 0);
    }

    // ---- epilogue: every lane holds l(q=lm) in o5
    const float invl = 1.0f / o5[0];
    float* orow = out + (size_t)(b*SEQ + qb + wv*16 + lm)*DIM + h*64;
#pragma unroll
    for (int nb = 0; nb < 4; ++nb) {
        float4 vres;
        vres.x = o[nb][0] * invl;
        vres.y = o[nb][1] * invl;
        vres.z = o[nb][2] * invl;
        vres.w = o[nb][3] * invl;
        *(float4*)&orow[nb*16 + quad*4] = vres;
    }
}

// ---------------------------------------------------------------- launcher
extern "C" void kernel_launch(void* const* d_in, const int* in_sizes, int n_in,
                              void* d_out, int out_size, void* d_ws, size_t ws_size,
                              hipStream_t stream) {
    const float* x   = (const float*)d_in[0];
    const float* Wqk = (const float*)d_in[1];
    const float* bqk = (const float*)d_in[2];
    const float* Wv  = (const float*)d_in[3];
    const float* bv  = (const float*)d_in[4];
    float* out = (float*)d_out;

    char* ws = (char*)d_ws;
    const size_t SZ_XB = (size_t)MROWS*KDIM*2;    // 8 MB
    const size_t SZ_WT = (size_t)NTOT*KDIM*2;     // 6 MB
    const size_t SZ_F  = (size_t)MROWS*1024*2;    // 8 MB per frag buffer
    __bf16* xbF = (__bf16*)(ws);
    __bf16* WtF = (__bf16*)(ws + SZ_XB);
    __bf16* qF  = (__bf16*)(ws + SZ_XB + SZ_WT);
    __bf16* kF  = (__bf16*)(ws + SZ_XB + SZ_WT + SZ_F);
    __bf16* vF  = (__bf16*)(ws + SZ_XB + SZ_WT + 2*SZ_F);

    prep_kernel    <<<4096 + 768, 256, 0, stream>>>(x, Wqk, Wv, xbF, WtF);
    gemm_qkv_kernel<<<dim3(NTOT/BN, MROWS/BM), 320, 0, stream>>>(xbF, WtF, bqk, bv, qF, kF, vF);
    attn_kernel    <<<dim3(32, 32), 320, 0, stream>>>(qF, kF, vF, out);
}

// Round 17
// 151.461 us; speedup vs baseline: 1.0761x; 1.0761x over previous
//
#include <hip/hip_runtime.h>
#include <hip/hip_bf16.h>
#include <math.h>

// Problem constants
#define BATCH 2
#define SEQ   2048
#define DIM   1024
#define HEADS 16
#define DH    64
#define MROWS (BATCH*SEQ)      // 4096
#define NTOT  3072             // gemm output cols: q(1024) | k(1024) | v(1024)
#define KDIM  1024

typedef float f32x4 __attribute__((ext_vector_type(4)));
typedef __bf16 bf16x8 __attribute__((ext_vector_type(8)));
typedef __bf16 bf16x4 __attribute__((ext_vector_type(4)));

// Fragment-order OUTPUT buffers (1KB block = 64 lanes x 16B; lane ln = quad*16 + (row&15)):
//  qF/kF: block ((b*128+g)*16 + h)*2 + kf      g = token-group (16 tokens)
//  vF   : block ((bh*32+kvt)*4 + nb)*2 + kf    kvt = kv/64, dv-group nb
// One block == one global_load_lds (wave-uniform dest, lane*16B) == one natural b128 read.

__device__ __forceinline__ void gload_lds16(const void* g, void* l) {
    __builtin_amdgcn_global_load_lds((__attribute__((address_space(1))) void*)g,
                                     (__attribute__((address_space(3))) void*)l,
                                     16, 0, 0);
}

// ---------------------------------------------- prep: cast x -> bf16  +  transpose W -> Wt
__global__ void prep_kernel(const float* __restrict__ x,
                            const float* __restrict__ Wqk, const float* __restrict__ Wv,
                            __bf16* __restrict__ xb, __bf16* __restrict__ Wt) {
    __shared__ float T[64*65];
    const int bx = blockIdx.x;
    const int tid = threadIdx.x;
    if (bx < 4096) {
        int i = bx * 256 + tid;                   // 1M float4 = 4M floats exactly
        float4 f = ((const float4*)x)[i];
        bf16x4 o;
        o.x = (__bf16)f.x; o.y = (__bf16)f.y; o.z = (__bf16)f.z; o.w = (__bf16)f.w;
        ((bf16x4*)xb)[i] = o;
    } else {
        const int t = bx - 4096;                  // 0..767
        const int n0 = (t % 48) * 64;
        const int k0 = (t / 48) * 64;
#pragma unroll
        for (int i = 0; i < 16; ++i) {
            int idx = i*256 + tid;
            int kk = idx >> 6, nn = idx & 63;
            int n = n0 + nn;
            float v = (n < 2048) ? Wqk[(size_t)(k0+kk)*2048 + n]
                                 : Wv [(size_t)(k0+kk)*1024 + (n - 2048)];
            T[kk*65 + nn] = v;
        }
        __syncthreads();
#pragma unroll
        for (int i = 0; i < 16; ++i) {
            int idx = i*256 + tid;
            int nn = idx >> 6, kk = idx & 63;
            Wt[(size_t)(n0+nn)*KDIM + k0 + kk] = (__bf16)T[kk*65 + nn];
        }
    }
}

// ---------------------------------------------------------------- GEMM (r14/r11 core)
// BK=64 single-buffer LDS + XOR swizzle. qk path computes C^T (bit-identical sums);
// epilogues scatter into qF/kF/vF fragment-order (256B store segments).
#define BM 128
#define BN 128
#define BK 64

__global__ __launch_bounds__(256, 3) void gemm_qkv_kernel(const __bf16* __restrict__ A,
                                                          const __bf16* __restrict__ Bt,
                                                          const float* __restrict__ bqk,
                                                          const float* __restrict__ bv,
                                                          __bf16* __restrict__ qF,
                                                          __bf16* __restrict__ kF,
                                                          __bf16* __restrict__ vF) {
    __shared__ alignas(16) __bf16 As[BM*BK];
    __shared__ alignas(16) __bf16 Bs[BN*BK];
    const int tid = threadIdx.x;
    const int wv = tid >> 6, ln = tid & 63;
    const int quad = ln >> 4, lm = ln & 15;
    const int m0 = blockIdx.y * BM, n0 = blockIdx.x * BN;
    const int wm = (wv >> 1) * 64, wn = (wv & 1) * 64;
    const int sw = lm & 7;

    f32x4 acc[4][4] = {};

    if (n0 < 2048) {
        // ---------------- q/k path: acc[nt][mt] = C^T tiles ----------------
        for (int kt = 0; kt < KDIM/BK; ++kt) {
            const int k0 = kt * BK;
            __syncthreads();
#pragma unroll
            for (int i = 0; i < 4; ++i) {
                int slot = wv*256 + i*64 + ln;
                int row = slot >> 3, p = slot & 7;
                int cc = (p ^ (row & 7)) * 8;
                gload_lds16(A  + (size_t)(m0 + row)*KDIM + k0 + cc, &As[(wv*256 + i*64)*8]);
                gload_lds16(Bt + (size_t)(n0 + row)*KDIM + k0 + cc, &Bs[(wv*256 + i*64)*8]);
            }
            __syncthreads();
#pragma unroll
            for (int kf = 0; kf < 2; ++kf) {
                bf16x8 af[4], bfr[4];
#pragma unroll
                for (int mt = 0; mt < 4; ++mt)
                    af[mt] = *(const bf16x8*)&As[(wm + mt*16 + lm)*BK + (((kf<<2)|quad) ^ sw)*8];
#pragma unroll
                for (int nt = 0; nt < 4; ++nt)
                    bfr[nt] = *(const bf16x8*)&Bs[(wn + nt*16 + lm)*BK + (((kf<<2)|quad) ^ sw)*8];
#pragma unroll
                for (int nt = 0; nt < 4; ++nt)
#pragma unroll
                    for (int mt = 0; mt < 4; ++mt)
                        acc[nt][mt] = __builtin_amdgcn_mfma_f32_16x16x32_bf16(bfr[nt], af[mt], acc[nt][mt], 0, 0, 0);
            }
        }
        __bf16* dst = (n0 < 1024) ? qF : kF;        // block-uniform
#pragma unroll
        for (int nt = 0; nt < 4; ++nt) {
            int f = n0 + wn + nt*16 + quad*4;
            float4 bs4 = *(const float4*)&bqk[f];
            int fl = f & 1023;
            int h  = fl >> 6;
            int ff = fl & 63;
            int fquad = (ff >> 3) & 3;
            int j0 = ff & 7;
            int kf = ff >> 5;
#pragma unroll
            for (int mt = 0; mt < 4; ++mt) {
                int m = m0 + wm + mt*16 + lm;
                int b = m >> 11, g = (m & 2047) >> 4;
                bf16x4 pk;
                pk[0] = (__bf16)(acc[nt][mt][0] + bs4.x);
                pk[1] = (__bf16)(acc[nt][mt][1] + bs4.y);
                pk[2] = (__bf16)(acc[nt][mt][2] + bs4.z);
                pk[3] = (__bf16)(acc[nt][mt][3] + bs4.w);
                size_t blk = (((size_t)(b*128 + g)*16 + h)*2 + kf);
                *(bf16x4*)&dst[blk*512 + (fquad*16 + lm)*8 + j0] = pk;
            }
        }
    } else {
        // ---------------- v path: acc[mt][nt] = C tiles -> vF frag-order ----------------
        for (int kt = 0; kt < KDIM/BK; ++kt) {
            const int k0 = kt * BK;
            __syncthreads();
#pragma unroll
            for (int i = 0; i < 4; ++i) {
                int slot = wv*256 + i*64 + ln;
                int row = slot >> 3, p = slot & 7;
                int cc = (p ^ (row & 7)) * 8;
                gload_lds16(A  + (size_t)(m0 + row)*KDIM + k0 + cc, &As[(wv*256 + i*64)*8]);
                gload_lds16(Bt + (size_t)(n0 + row)*KDIM + k0 + cc, &Bs[(wv*256 + i*64)*8]);
            }
            __syncthreads();
#pragma unroll
            for (int kf = 0; kf < 2; ++kf) {
                bf16x8 af[4], bfr[4];
#pragma unroll
                for (int mt = 0; mt < 4; ++mt)
                    af[mt] = *(const bf16x8*)&As[(wm + mt*16 + lm)*BK + (((kf<<2)|quad) ^ sw)*8];
#pragma unroll
                for (int nt = 0; nt < 4; ++nt)
                    bfr[nt] = *(const bf16x8*)&Bs[(wn + nt*16 + lm)*BK + (((kf<<2)|quad) ^ sw)*8];
#pragma unroll
                for (int mt = 0; mt < 4; ++mt)
#pragma unroll
                    for (int nt = 0; nt < 4; ++nt)
                        acc[mt][nt] = __builtin_amdgcn_mfma_f32_16x16x32_bf16(af[mt], bfr[nt], acc[mt][nt], 0, 0, 0);
            }
        }
#pragma unroll
        for (int mt = 0; mt < 4; ++mt) {
            int s4 = m0 + wm + mt*16 + quad*4;
            int b   = s4 >> 11;
            int kvt = (s4 & 2047) >> 6;
            int kv  = s4 & 63;
            int kf  = kv >> 5;
            int qv  = (kv >> 3) & 3;
            int j0  = kv & 7;
#pragma unroll
            for (int nt = 0; nt < 4; ++nt) {
                int cv = n0 + wn + nt*16 + lm - 2048;
                int h = cv >> 6, dv = cv & 63, nb = dv >> 4;
                float bs = bv[cv];
                bf16x4 pk;
#pragma unroll
                for (int r = 0; r < 4; ++r) pk[r] = (__bf16)(acc[mt][nt][r] + bs);
                size_t blk = (((size_t)((b*16 + h)*32 + kvt)*4 + nb)*2 + kf);
                *(bf16x4*)&vF[blk*512 + (qv*16 + lm)*8 + j0] = pk;
            }
        }
    }
}

// ---------------------------------------------------------------- flash attention (r14 best)
// 4-wave blocks + frag-order K/V staged into SHARED LDS (single global_load_lds per 1KB
// block; lane*16 dest IS the frag layout). Natural conflict-free b128 frag reads. Dbuf;
// exp2 no-max softmax + ones-MFMA l. grid (32 bh, 32 qt heavy-first); LDS 40KB -> 4 blk/CU.

__global__ __launch_bounds__(256, 4) void attn_kernel(const __bf16* __restrict__ qF,
                                                      const __bf16* __restrict__ kF,
                                                      const __bf16* __restrict__ vF,
                                                      float* __restrict__ out) {
    const int bh = blockIdx.x;
    const int b = bh >> 4, h = bh & 15;
    const int qt = 31 - (int)blockIdx.y;            // heavy blocks dispatched first
    const int qb = qt * 64;
    const int tid = threadIdx.x, wv = tid >> 6, ln = tid & 63;
    const int quad = ln >> 4, lm = ln & 15;
    const int q0w = qb + wv*16;                     // this wave's 16 q-rows
    const int qg = q0w + lm;                        // this lane's q row

    __shared__ alignas(16) __bf16 Ks[2][8*512];     // [buf][slot nt*2+kf][frag]
    __shared__ alignas(16) __bf16 Vs[2][8*512];     // [buf][slot nb*2+kf][frag]
    __shared__ alignas(16) __bf16 Ps[4][16*64];     // per-wave P^T [q][kv], chunk-swizzled

    const int sw = lm & 7;                          // P swizzle key

    // staging: wave wv stages 4 of the 16 frag blocks (wv 0,1 -> K slots, wv 2,3 -> V slots)
    auto issue = [&](int st, int buf) {
#pragma unroll
        for (int i = 0; i < 4; ++i) {
            int idx = wv*4 + i;                     // 0..15, wave-uniform branch below
            if (idx < 8) {
                int nt = idx >> 1, kf = idx & 1;
                const __bf16* g = kF + ((((size_t)b*128 + st*4 + nt)*16 + h)*2 + kf)*512 + (size_t)ln*8;
                gload_lds16(g, &Ks[buf][idx*512]);
            } else {
                int j = idx - 8;
                int nb = j >> 1, kf = j & 1;
                const __bf16* g = vF + ((((size_t)bh*32 + st)*4 + nb)*2 + kf)*512 + (size_t)ln*8;
                gload_lds16(g, &Vs[buf][j*512]);
            }
        }
    };

    // Q fragments, pre-scaled by 0.125*log2(e) so P = exp2(S)
    const float qscale = 0.125f * 1.44269504088896f;
    bf16x8 qf[2];
#pragma unroll
    for (int kf = 0; kf < 2; ++kf) {
        bf16x8 t = *(const bf16x8*)&qF[((((size_t)b*128 + (q0w >> 4))*16 + h)*2 + kf)*512 + ln*8];
#pragma unroll
        for (int j = 0; j < 8; ++j) t[j] = (__bf16)((float)t[j] * qscale);
        qf[kf] = t;
    }
    bf16x8 ones;
#pragma unroll
    for (int j = 0; j < 8; ++j) ones[j] = (__bf16)1.0f;

    f32x4 o[4] = {};                                // O^T: (dv = nb*16+quad*4+r, q = lm)
    f32x4 o5 = {};                                  // l accumulator: every reg = l(q=lm)
    const int nsteps = qt + 1;

    issue(0, 0);                                    // prologue prefetch
    for (int st = 0; st < nsteps; ++st) {
        const int cur = st & 1;
        const int kv0 = st * 64;
        __syncthreads();                            // drains buf[cur] loads; frees buf[cur^1]
        if (st + 1 < nsteps) issue(st + 1, cur ^ 1);// prefetch flies during this step's compute

        // ---- S^T = K Q^T : frag reads are natural b128, conflict-free
        f32x4 s[4] = {};
        bf16x8 kfrag[4][2];
#pragma unroll
        for (int nt = 0; nt < 4; ++nt)
#pragma unroll
            for (int kf = 0; kf < 2; ++kf)
                kfrag[nt][kf] = *(const bf16x8*)&Ks[cur][(nt*2 + kf)*512 + ln*8];
#pragma unroll
        for (int nt = 0; nt < 4; ++nt)
#pragma unroll
            for (int kf = 0; kf < 2; ++kf)
                s[nt] = __builtin_amdgcn_mfma_f32_16x16x32_bf16(kfrag[nt][kf], qf[kf], s[nt], 0, 0, 0);

        // ---- causal mask (diagonal step only; exp2(-1e9)=0)
        if (kv0 + 63 > q0w) {
#pragma unroll
            for (int nt = 0; nt < 4; ++nt)
#pragma unroll
                for (int r = 0; r < 4; ++r) {
                    int kvg = kv0 + nt*16 + quad*4 + r;
                    if (kvg > qg) s[nt][r] = -1e9f;
                }
        }

        // ---- P = exp2(s) -> per-wave LDS (swizzled 8B stores)
#pragma unroll
        for (int nt = 0; nt < 4; ++nt) {
            bf16x4 pb;
#pragma unroll
            for (int r = 0; r < 4; ++r)
                pb[r] = (__bf16)exp2f(s[nt][r]);
            int pos = ((nt*2 + (quad >> 1)) ^ sw);
            *(bf16x4*)&Ps[wv][lm*64 + pos*8 + (quad & 1)*4] = pb;
        }

        // ---- O^T += V^T P^T ; l += 1^T P^T  (wave-local LDS RAW)
        bf16x8 vfrag[4][2];
#pragma unroll
        for (int nb = 0; nb < 4; ++nb)
#pragma unroll
            for (int kf = 0; kf < 2; ++kf)
                vfrag[nb][kf] = *(const bf16x8*)&Vs[cur][(nb*2 + kf)*512 + ln*8];
        bf16x8 pf0 = *(const bf16x8*)&Ps[wv][lm*64 + ((0*4 + quad) ^ sw)*8];
        bf16x8 pf1 = *(const bf16x8*)&Ps[wv][lm*64 + ((1*4 + quad) ^ sw)*8];
#pragma unroll
        for (int nb = 0; nb < 4; ++nb) {
            o[nb] = __builtin_amdgcn_mfma_f32_16x16x32_bf16(vfrag[nb][0], pf0, o[nb], 0, 0, 0);
            o[nb] = __builtin_amdgcn_mfma_f32_16x16x32_bf16(vfrag[nb][1], pf1, o[nb], 0, 0, 0);
        }
        o5 = __builtin_amdgcn_mfma_f32_16x16x32_bf16(ones, pf0, o5, 0, 0, 0);
        o5 = __builtin_amdgcn_mfma_f32_16x16x32_bf16(ones, pf1, o5, 0, 0, 0);
    }

    // ---- epilogue: every lane holds l(q=lm) in o5
    const float invl = 1.0f / o5[0];
    float* orow = out + (size_t)(b*SEQ + q0w + lm)*DIM + h*64;
#pragma unroll
    for (int nb = 0; nb < 4; ++nb) {
        float4 vres;
        vres.x = o[nb][0] * invl;
        vres.y = o[nb][1] * invl;
        vres.z = o[nb][2] * invl;
        vres.w = o[nb][3] * invl;
        *(float4*)&orow[nb*16 + quad*4] = vres;
    }
}

// ---------------------------------------------------------------- launcher
extern "C" void kernel_launch(void* const* d_in, const int* in_sizes, int n_in,
                              void* d_out, int out_size, void* d_ws, size_t ws_size,
                              hipStream_t stream) {
    const float* x   = (const float*)d_in[0];
    const float* Wqk = (const float*)d_in[1];
    const float* bqk = (const float*)d_in[2];
    const float* Wv  = (const float*)d_in[3];
    const float* bv  = (const float*)d_in[4];
    float* out = (float*)d_out;

    char* ws = (char*)d_ws;
    const size_t SZ_XB = (size_t)MROWS*KDIM*2;    // 8 MB
    const size_t SZ_WT = (size_t)NTOT*KDIM*2;     // 6 MB
    const size_t SZ_F  = (size_t)MROWS*1024*2;    // 8 MB per frag buffer
    __bf16* xb = (__bf16*)(ws);
    __bf16* Wt = (__bf16*)(ws + SZ_XB);
    __bf16* qF = (__bf16*)(ws + SZ_XB + SZ_WT);
    __bf16* kF = (__bf16*)(ws + SZ_XB + SZ_WT + SZ_F);
    __bf16* vF = (__bf16*)(ws + SZ_XB + SZ_WT + 2*SZ_F);

    prep_kernel    <<<4096 + 768, 256, 0, stream>>>(x, Wqk, Wv, xb, Wt);
    gemm_qkv_kernel<<<dim3(NTOT/BN, MROWS/BM), 256, 0, stream>>>(xb, Wt, bqk, bv, qF, kF, vF);
    attn_kernel    <<<dim3(32, 32), 256, 0, stream>>>(qF, kF, vF, out);
}